// Round 4
// baseline (1070.710 us; speedup 1.0000x reference)
//
#include <hip/hip_runtime.h>
#include <cstdint>
#include <cstddef>

#define Bn 8
#define Tn 8192
#define BT (Bn*Tn)      // 65536 points
#define Hn 128
#define RRn 16384       // 128*128 bins per plane per batch

typedef unsigned short u16;
typedef __attribute__((ext_vector_type(8))) short s8v;   // 8 bf16 (4 VGPRs)
typedef __attribute__((ext_vector_type(4))) float f4v;   // 4 f32 acc

__device__ __forceinline__ u16 f2bf(float f) {
  unsigned u = __float_as_uint(f);
  unsigned r = (u + 0x7FFF + ((u >> 16) & 1)) >> 16;   // RNE
  return (u16)r;
}

__device__ __forceinline__ s8v relu8(s8v a) {
  union { s8v s; unsigned u[4]; } x; x.s = a;
#pragma unroll
  for (int k = 0; k < 4; ++k) {
    unsigned m = ((x.u[k] & 0x80008000u) >> 15) * 0xFFFFu;
    x.u[k] &= ~m;
  }
  return x.s;
}

__device__ __forceinline__ void upk(unsigned u, float& lo, float& hi) {
  lo = __uint_as_float(u << 16);
  hi = __uint_as_float(u & 0xFFFF0000u);
}

// ---------------- index computation ----------------
__global__ void k_idx(const float* __restrict__ p, int* __restrict__ idx) {
  int i = blockIdx.x*256 + threadIdx.x;
  if (i >= BT) return;
  float v0 = p[i*3+0], v1 = p[i*3+1], v2 = p[i*3+2];
  float v[3] = {v0, v1, v2};
  const int A0[3] = {0,0,1};
  const int A1[3] = {2,1,2};
#pragma unroll
  for (int pl = 0; pl < 3; ++pl) {
    float a = v[A0[pl]] / 1.001f + 0.5f;
    float b = v[A1[pl]] / 1.001f + 0.5f;
    a = fminf(fmaxf(a, 0.0f), 0.999f);
    b = fminf(fmaxf(b, 0.0f), 0.999f);
    int ga = (int)floorf(a * 128.0f);
    int gb = (int)floorf(b * 128.0f);
    idx[pl*BT + i] = ga + 128*gb;
  }
}

// ---------------- CSR build ----------------
__global__ void k_hist(const int* __restrict__ idx, int* __restrict__ cnt32) {
  int g = blockIdx.x*256 + threadIdx.x;
  if (g >= 3*BT) return;
  int pl = g >> 16, i = g & (BT-1);
  int b = i >> 13;
  atomicAdd(&cnt32[(pl*Bn + b)*RRn + idx[g]], 1);
}

__global__ void k_scan(const int* __restrict__ cnt32, int* __restrict__ starts,
                       int* __restrict__ cursor) {
  int seg = blockIdx.x;                 // 0..23
  const int* c = cnt32 + seg*RRn;
  int* st = starts + seg*RRn;
  int* cu = cursor + seg*RRn;
  int t = threadIdx.x;
  __shared__ int part[256];
  int base = t*64;
  int sum = 0;
#pragma unroll 8
  for (int j = 0; j < 64; ++j) sum += c[base+j];
  part[t] = sum; __syncthreads();
  for (int ofs = 1; ofs < 256; ofs <<= 1) {
    int v = (t >= ofs) ? part[t-ofs] : 0;
    __syncthreads();
    part[t] += v;
    __syncthreads();
  }
  int run = (t ? part[t-1] : 0) + seg*Tn;
#pragma unroll 8
  for (int j = 0; j < 64; ++j) { st[base+j] = run; cu[base+j] = run; run += c[base+j]; }
}

__global__ void k_fill(const int* __restrict__ idx, int* __restrict__ cursor,
                       int* __restrict__ sorted) {
  int g = blockIdx.x*256 + threadIdx.x;
  if (g >= 3*BT) return;
  int pl = g >> 16, i = g & (BT-1);
  int b = i >> 13;
  int pos = atomicAdd(&cursor[(pl*Bn + b)*RRn + idx[g]], 1);
  sorted[pos] = i;
}

// ---------------- weight prep: f32 [k][n] -> bf16 [n][k], 52 chunks of 128x128 ----
__global__ void k_prep(const float* __restrict__ bw0, const float* __restrict__ bw1,
                       const float* __restrict__ bws, const float* __restrict__ cw0,
                       const float* __restrict__ cw1, const float* __restrict__ cws,
                       const float* __restrict__ fcw, const float* __restrict__ fccw,
                       u16* __restrict__ arena) {
  int c = blockIdx.x;            // 0..51
  int s = c / 26, r = c % 26;
  const float* base;
  if (r < 10)      base = (s ? cw0 : bw0) + (size_t)(r >> 1)*32768 + (size_t)(r & 1)*16384;
  else if (r < 15) base = (s ? cw1 : bw1) + (size_t)(r - 10)*16384;
  else if (r < 25) base = (s ? cws : bws) + (size_t)((r - 15) >> 1)*32768 + (size_t)((r - 15) & 1)*16384;
  else             base = s ? fccw : fcw;
  __shared__ u16 ld[128*130];
#pragma unroll 4
  for (int it = 0; it < 64; ++it) {
    int lin = it*256 + threadIdx.x;
    int k = lin >> 7, n = lin & 127;
    ld[k*130 + n] = f2bf(base[lin]);
  }
  __syncthreads();
  u16* dst = arena + (size_t)c*16384;
#pragma unroll 4
  for (int it = 0; it < 64; ++it) {
    int lin = it*256 + threadIdx.x;
    int n = lin >> 7, k = lin & 127;
    dst[lin] = ld[k*130 + n];
  }
}

// ---------------- input projection (bf16 out, 8 ch/thread) ----------------
__global__ void k_proj(const float* __restrict__ p, const float* __restrict__ p2,
                       const float* __restrict__ wp, const float* __restrict__ bp,
                       const float* __restrict__ wp2, const float* __restrict__ bp2,
                       u16* __restrict__ outLo, u16* __restrict__ outHi, int corr) {
  int g = blockIdx.x*256 + threadIdx.x;   // BT*32
  int i = g >> 5, c8 = (g & 31) * 8;
  if (i >= BT) return;
  float a0 = p[i*3+0], a1 = p[i*3+1], a2 = p[i*3+2];
  float q0 = 0.f, q1 = 0.f, q2 = 0.f;
  if (corr) { q0 = p2[i*3+0]; q1 = p2[i*3+1]; q2 = p2[i*3+2]; }
  union { uint4 v; unsigned u[4]; } o;
#pragma unroll
  for (int k2 = 0; k2 < 4; ++k2) {
    float r[2];
#pragma unroll
    for (int t = 0; t < 2; ++t) {
      int c = c8 + k2*2 + t;
      float v = a0*wp[c] + a1*wp[256+c] + a2*wp[512+c] + bp[c];
      if (corr) v += q0*wp2[c] + q1*wp2[256+c] + q2*wp2[512+c] + bp2[c];
      r[t] = v;
    }
    o.u[k2] = (unsigned)f2bf(r[0]) | ((unsigned)f2bf(r[1]) << 16);
  }
  u16* dst = (c8 < 128) ? (outLo + (size_t)i*128 + c8)
                        : (outHi + (size_t)i*128 + (c8 - 128));
  *(uint4*)dst = o.v;
}

// ---------------- fused ResNet block (XOR-swizzled LDS, 80 KB -> 2 blocks/CU) ----
// x = [xA | xB] (each [BT][128] bf16), K=256.
// hidden = relu( relu(x) @ w0 + b0 )   (LDS only)
// out    = x @ ws + hidden @ w1 + b1
// FC: cout = out @ fcw + fcb          (out never hits global)
template<bool FC>
__global__ __launch_bounds__(512, 4) void k_rb(
    const u16* __restrict__ xA, const u16* __restrict__ xB,
    const u16* __restrict__ w00, const u16* __restrict__ w01,
    const u16* __restrict__ ws0, const u16* __restrict__ ws1,
    const u16* __restrict__ w1c,
    const float* __restrict__ b0, const float* __restrict__ b1,
    const u16* __restrict__ fcw, const float* __restrict__ fcb,
    u16* __restrict__ outp)
{
  __shared__ u16 xs [128*64];   // [row][k0..63], byte ^= ((row&7)<<4)
  __shared__ u16 wH [128*64];   // fc0 weight chunk [n][k]
  __shared__ u16 wS [128*64];   // shortcut weight chunk [n][k]
  __shared__ u16 hid[128*128];  // [row][col], byte ^= ((row&7)<<4)
  const int tid = threadIdx.x;
  const size_t row0 = (size_t)blockIdx.x * 128;
  const int l = tid & 63, w = tid >> 6;     // 8 waves, 16 rows each
  const int lm = l & 15, lg = l >> 4;
  const int trow = tid >> 2, tq = tid & 3;  // staging: 32B/thread/buffer
  const int ssw = (trow & 7) << 4;          // staging swizzle
  const int rsw = (lm & 7) << 4;            // read swizzle (rows are w*16+lm)

  f4v acc_h[8], acc_s[8];
#pragma unroll
  for (int j = 0; j < 8; ++j) { acc_h[j] = (f4v){0,0,0,0}; acc_s[j] = (f4v){0,0,0,0}; }

#pragma unroll 1
  for (int kc = 0; kc < 4; ++kc) {
    const u16* xsrc  = (kc < 2) ? xA  : xB;
    const u16* w0src = (kc < 2) ? w00 : w01;
    const u16* wssrc = (kc < 2) ? ws0 : ws1;
    const int k0 = (kc & 1) * 64;
    __syncthreads();
    {
      const u16* s1 = xsrc + (row0 + trow)*128 + k0 + tq*16;
      *(uint4*)((char*)xs + trow*128 + ((tq*32     ) ^ ssw)) = ((const uint4*)s1)[0];
      *(uint4*)((char*)xs + trow*128 + ((tq*32 + 16) ^ ssw)) = ((const uint4*)s1)[1];
      const u16* s2 = w0src + trow*128 + k0 + tq*16;
      *(uint4*)((char*)wH + trow*128 + ((tq*32     ) ^ ssw)) = ((const uint4*)s2)[0];
      *(uint4*)((char*)wH + trow*128 + ((tq*32 + 16) ^ ssw)) = ((const uint4*)s2)[1];
      const u16* s3 = wssrc + trow*128 + k0 + tq*16;
      *(uint4*)((char*)wS + trow*128 + ((tq*32     ) ^ ssw)) = ((const uint4*)s3)[0];
      *(uint4*)((char*)wS + trow*128 + ((tq*32 + 16) ^ ssw)) = ((const uint4*)s3)[1];
    }
    __syncthreads();
#pragma unroll
    for (int kk = 0; kk < 2; ++kk) {
      const int ko = (kk*64 + lg*16) ^ rsw;
      s8v a  = *(const s8v*)((const char*)xs + (w*16 + lm)*128 + ko);
      s8v ar = relu8(a);
#pragma unroll
      for (int nj = 0; nj < 8; ++nj) {
        s8v bh = *(const s8v*)((const char*)wH + (nj*16 + lm)*128 + ko);
        acc_h[nj] = __builtin_amdgcn_mfma_f32_16x16x32_bf16(ar, bh, acc_h[nj], 0, 0, 0);
      }
#pragma unroll
      for (int nj = 0; nj < 8; ++nj) {
        s8v bs = *(const s8v*)((const char*)wS + (nj*16 + lm)*128 + ko);
        acc_s[nj] = __builtin_amdgcn_mfma_f32_16x16x32_bf16(a, bs, acc_s[nj], 0, 0, 0);
      }
    }
  }
  __syncthreads();   // all pass-1 LDS reads done
  // stage w1 into wH(k0-63)/wS(k64-127); write hid = relu(acc_h + b0)
  {
    const u16* s1 = w1c + trow*128 + tq*16;
    *(uint4*)((char*)wH + trow*128 + ((tq*32     ) ^ ssw)) = ((const uint4*)s1)[0];
    *(uint4*)((char*)wH + trow*128 + ((tq*32 + 16) ^ ssw)) = ((const uint4*)s1)[1];
    const u16* s2 = w1c + trow*128 + 64 + tq*16;
    *(uint4*)((char*)wS + trow*128 + ((tq*32     ) ^ ssw)) = ((const uint4*)s2)[0];
    *(uint4*)((char*)wS + trow*128 + ((tq*32 + 16) ^ ssw)) = ((const uint4*)s2)[1];
#pragma unroll
    for (int nj = 0; nj < 8; ++nj) {
      const float bv = b0[nj*16 + lm];
#pragma unroll
      for (int r = 0; r < 4; ++r) {
        int row = w*16 + lg*4 + r;
        int cb = (nj*32 + lm*2) ^ ((row & 7) << 4);
        *(u16*)((char*)hid + row*256 + cb) = f2bf(fmaxf(acc_h[nj][r] + bv, 0.0f));
      }
    }
  }
  __syncthreads();
  // pass 2: acc_s += hidden @ w1
#pragma unroll
  for (int kk = 0; kk < 4; ++kk) {
    const int koA = (kk*64 + lg*16) ^ rsw;
    const int koB = ((kk & 1)*64 + lg*16) ^ rsw;
    const char* wb = (const char*)((kk < 2) ? wH : wS);
    s8v a = *(const s8v*)((const char*)hid + (w*16 + lm)*256 + koA);
#pragma unroll
    for (int nj = 0; nj < 8; ++nj) {
      s8v bb = *(const s8v*)(wb + (nj*16 + lm)*128 + koB);
      acc_s[nj] = __builtin_amdgcn_mfma_f32_16x16x32_bf16(a, bb, acc_s[nj], 0, 0, 0);
    }
  }
  if (!FC) {
#pragma unroll
    for (int nj = 0; nj < 8; ++nj) {
      const int col = nj*16 + lm;
      const float bv = b1[col];
#pragma unroll
      for (int r = 0; r < 4; ++r) {
        int row = w*16 + lg*4 + r;
        outp[(row0 + row)*128 + col] = f2bf(acc_s[nj][r] + bv);
      }
    }
  } else {
    __syncthreads();   // pass-2 reads of hid/wH/wS done
    // write out into hid; stage fcw
    {
      const u16* s1 = fcw + trow*128 + tq*16;
      *(uint4*)((char*)wH + trow*128 + ((tq*32     ) ^ ssw)) = ((const uint4*)s1)[0];
      *(uint4*)((char*)wH + trow*128 + ((tq*32 + 16) ^ ssw)) = ((const uint4*)s1)[1];
      const u16* s2 = fcw + trow*128 + 64 + tq*16;
      *(uint4*)((char*)wS + trow*128 + ((tq*32     ) ^ ssw)) = ((const uint4*)s2)[0];
      *(uint4*)((char*)wS + trow*128 + ((tq*32 + 16) ^ ssw)) = ((const uint4*)s2)[1];
#pragma unroll
      for (int nj = 0; nj < 8; ++nj) {
        const float bv = b1[nj*16 + lm];
#pragma unroll
        for (int r = 0; r < 4; ++r) {
          int row = w*16 + lg*4 + r;
          int cb = (nj*32 + lm*2) ^ ((row & 7) << 4);
          *(u16*)((char*)hid + row*256 + cb) = f2bf(acc_s[nj][r] + bv);
        }
      }
    }
    __syncthreads();
    f4v accf[8];
#pragma unroll
    for (int j = 0; j < 8; ++j) accf[j] = (f4v){0,0,0,0};
#pragma unroll
    for (int kk = 0; kk < 4; ++kk) {
      const int koA = (kk*64 + lg*16) ^ rsw;
      const int koB = ((kk & 1)*64 + lg*16) ^ rsw;
      const char* wb = (const char*)((kk < 2) ? wH : wS);
      s8v a = *(const s8v*)((const char*)hid + (w*16 + lm)*256 + koA);
#pragma unroll
      for (int nj = 0; nj < 8; ++nj) {
        s8v bb = *(const s8v*)(wb + (nj*16 + lm)*128 + koB);
        accf[nj] = __builtin_amdgcn_mfma_f32_16x16x32_bf16(a, bb, accf[nj], 0, 0, 0);
      }
    }
#pragma unroll
    for (int nj = 0; nj < 8; ++nj) {
      const int col = nj*16 + lm;
      const float bv = fcb[col];
#pragma unroll
      for (int r = 0; r < 4; ++r) {
        int row = w*16 + lg*4 + r;
        outp[(row0 + row)*128 + col] = f2bf(accf[nj][r] + bv);
      }
    }
  }
}

// ---------------- CSR pooling: pooled[i] = sum_pl max_{j in bin(i,pl)} net[j] ----
__global__ void k_pool(const int* __restrict__ idx, const int* __restrict__ starts,
                       const int* __restrict__ cnt32, const int* __restrict__ sorted,
                       const u16* __restrict__ net, u16* __restrict__ pooled) {
  int g = blockIdx.x*256 + threadIdx.x;    // BT*16
  int sl = g & 15;
  int i = g >> 4;
  if (i >= BT) return;
  int b = i >> 13;
  float acc[8];
#pragma unroll
  for (int k = 0; k < 8; ++k) acc[k] = 0.0f;
#pragma unroll
  for (int pl = 0; pl < 3; ++pl) {
    int seg = (pl*Bn + b)*RRn + idx[pl*BT + i];
    int s = starts[seg];
    int e = s + cnt32[seg];
    float mx[8];
#pragma unroll
    for (int k = 0; k < 8; ++k) mx[k] = -3.0e38f;
    for (int j = s; j < e; ++j) {
      int jj = sorted[j];
      uint4 v = *(const uint4*)(net + (size_t)jj*128 + sl*8);
      float lo, hi;
      upk(v.x, lo, hi); mx[0] = fmaxf(mx[0], lo); mx[1] = fmaxf(mx[1], hi);
      upk(v.y, lo, hi); mx[2] = fmaxf(mx[2], lo); mx[3] = fmaxf(mx[3], hi);
      upk(v.z, lo, hi); mx[4] = fmaxf(mx[4], lo); mx[5] = fmaxf(mx[5], hi);
      upk(v.w, lo, hi); mx[6] = fmaxf(mx[6], lo); mx[7] = fmaxf(mx[7], hi);
    }
#pragma unroll
    for (int k = 0; k < 8; ++k) acc[k] += mx[k];
  }
  union { uint4 v; unsigned u[4]; } o;
#pragma unroll
  for (int k = 0; k < 4; ++k)
    o.u[k] = (unsigned)f2bf(acc[2*k]) | ((unsigned)f2bf(acc[2*k+1]) << 16);
  *(uint4*)(pooled + (size_t)i*128 + sl*8) = o.v;
}

// ---------------- CSR scatter-mean into output planes (writes empty bins = 0) ----
__global__ void k_mean(const int* __restrict__ starts, const int* __restrict__ cnt32,
                       const int* __restrict__ sorted, const u16* __restrict__ cbuf,
                       float* __restrict__ out, int planeBase) {
  int g = blockIdx.x*256 + threadIdx.x;    // 3*Bn*RRn*16
  int sl = g & 15;
  int bin = (g >> 4) & (RRn - 1);
  int r = g >> 18;
  int b = r & 7, pl = r >> 3;
  if (pl >= 3) return;
  int seg = (pl*Bn + b)*RRn + bin;
  int c = cnt32[seg];
  float sum[8];
#pragma unroll
  for (int k = 0; k < 8; ++k) sum[k] = 0.0f;
  int s = starts[seg];
  for (int j = s; j < s + c; ++j) {
    int jj = sorted[j];
    uint4 v = *(const uint4*)(cbuf + (size_t)jj*128 + sl*8);
    float lo, hi;
    upk(v.x, lo, hi); sum[0] += lo; sum[1] += hi;
    upk(v.y, lo, hi); sum[2] += lo; sum[3] += hi;
    upk(v.z, lo, hi); sum[4] += lo; sum[5] += hi;
    upk(v.w, lo, hi); sum[6] += lo; sum[7] += hi;
  }
  float inv = (c > 0) ? 1.0f / (float)c : 0.0f;
  int plane = planeBase + pl;
  size_t base = ((size_t)(plane*Bn + b)*Hn + sl*8)*RRn + bin;
#pragma unroll
  for (int k = 0; k < 8; ++k)
    out[base + (size_t)k*RRn] = sum[k] * inv;
}

// ---------------- host ----------------
extern "C" void kernel_launch(void* const* d_in, const int* in_sizes, int n_in,
                              void* d_out_v, int out_size, void* d_ws, size_t ws_size,
                              hipStream_t stream) {
  const float* p    = (const float*)d_in[0];
  const float* p2   = (const float*)d_in[1];
  const float* wp   = (const float*)d_in[2];
  const float* bp   = (const float*)d_in[3];
  const float* wp2  = (const float*)d_in[4];
  const float* bp2  = (const float*)d_in[5];
  const float* bw0  = (const float*)d_in[6];
  const float* bb0  = (const float*)d_in[7];
  const float* bw1  = (const float*)d_in[8];
  const float* bb1  = (const float*)d_in[9];
  const float* bws  = (const float*)d_in[10];
  const float* cw0  = (const float*)d_in[11];
  const float* cb0  = (const float*)d_in[12];
  const float* cw1  = (const float*)d_in[13];
  const float* cb1  = (const float*)d_in[14];
  const float* cws  = (const float*)d_in[15];
  const float* fcw  = (const float*)d_in[16];
  const float* fcb  = (const float*)d_in[17];
  const float* fccw = (const float*)d_in[18];
  const float* fccb = (const float*)d_in[19];
  float* out = (float*)d_out_v;

  size_t off = 0;
  auto alloc = [&](size_t bytes) -> char* {
    char* r = (char*)d_ws + off;
    off += (bytes + 255) & ~(size_t)255;
    return r;
  };
  int* idx    = (int*)alloc((size_t)3*BT*4);
  int* cnt32  = (int*)alloc((size_t)3*Bn*RRn*4);
  int* starts = (int*)alloc((size_t)3*Bn*RRn*4);
  int* cursor = (int*)alloc((size_t)3*Bn*RRn*4);
  int* sorted = (int*)alloc((size_t)3*BT*4);
  u16* arena  = (u16*)alloc((size_t)52*16384*2);
  u16* buf0   = (u16*)alloc((size_t)BT*128*2);
  u16* buf1   = (u16*)alloc((size_t)BT*128*2);
  u16* bufP   = (u16*)alloc((size_t)BT*128*2);
  u16* cbuf   = (u16*)alloc((size_t)BT*128*2);
  if (off > ws_size) return;

  hipMemsetAsync(cnt32, 0, (size_t)3*Bn*RRn*4, stream);
  k_prep<<<52, 256, 0, stream>>>(bw0, bw1, bws, cw0, cw1, cws, fcw, fccw, arena);
  k_idx <<<BT/256, 256, 0, stream>>>(p, idx);
  k_hist<<<(3*BT)/256, 256, 0, stream>>>(idx, cnt32);
  k_scan<<<24, 256, 0, stream>>>(cnt32, starts, cursor);
  k_fill<<<(3*BT)/256, 256, 0, stream>>>(idx, cursor, sorted);

  for (int s = 0; s < 2; ++s) {
    const float* B0 = s ? cb0 : bb0;
    const float* B1 = s ? cb1 : bb1;
    const float* FB = s ? fccb : fcb;
    auto WT = [&](int chunk) -> const u16* {
      return arena + (size_t)(s*26 + chunk)*16384;
    };

    k_proj<<<(BT*32)/256, 256, 0, stream>>>(p, p2, wp, bp, wp2, bp2, buf0, bufP, s);

    // block 0
    k_rb<false><<<BT/128, 512, 0, stream>>>(buf0, bufP, WT(0), WT(1), WT(15), WT(16),
                                            WT(10), B0, B1, nullptr, nullptr, buf1);
    u16* net = buf1; u16* other = buf0;
    for (int blk = 1; blk < 4; ++blk) {
      k_pool<<<(BT*16)/256, 256, 0, stream>>>(idx, starts, cnt32, sorted, net, bufP);
      k_rb<false><<<BT/128, 512, 0, stream>>>(net, bufP, WT(2*blk), WT(2*blk+1),
                                              WT(15+2*blk), WT(16+2*blk), WT(10+blk),
                                              B0 + blk*128, B1 + blk*128,
                                              nullptr, nullptr, other);
      u16* t = net; net = other; other = t;
    }
    // block 4 fused with final fc -> cbuf
    k_pool<<<(BT*16)/256, 256, 0, stream>>>(idx, starts, cnt32, sorted, net, bufP);
    k_rb<true><<<BT/128, 512, 0, stream>>>(net, bufP, WT(8), WT(9), WT(23), WT(24),
                                           WT(14), B0 + 4*128, B1 + 4*128,
                                           WT(25), FB, cbuf);
    // scatter-mean all 3 planes of this stream (also zero-fills empty bins)
    k_mean<<<(3*Bn*RRn*16)/256, 256, 0, stream>>>(starts, cnt32, sorted, cbuf, out, s*3);
  }
}

// Round 5
// 915.114 us; speedup vs baseline: 1.1700x; 1.1700x over previous
//
#include <hip/hip_runtime.h>
#include <cstdint>
#include <cstddef>

#define Bn 8
#define Tn 8192
#define BT (Bn*Tn)      // 65536 points
#define Hn 128
#define RRn 16384       // 128*128 bins per plane per batch

typedef unsigned short u16;
typedef __attribute__((ext_vector_type(8))) short s8v;   // 8 bf16 (4 VGPRs)
typedef __attribute__((ext_vector_type(4))) float f4v;   // 4 f32 acc

#define SSTR ((size_t)BT*128)   // per-stream activation stride (elements)

__device__ __forceinline__ u16 f2bf(float f) {
  unsigned u = __float_as_uint(f);
  unsigned r = (u + 0x7FFF + ((u >> 16) & 1)) >> 16;   // RNE
  return (u16)r;
}

__device__ __forceinline__ s8v relu8(s8v a) {
  union { s8v s; unsigned u[4]; } x; x.s = a;
#pragma unroll
  for (int k = 0; k < 4; ++k) {
    unsigned m = ((x.u[k] & 0x80008000u) >> 15) * 0xFFFFu;
    x.u[k] &= ~m;
  }
  return x.s;
}

__device__ __forceinline__ void upk(unsigned u, float& lo, float& hi) {
  lo = __uint_as_float(u << 16);
  hi = __uint_as_float(u & 0xFFFF0000u);
}

// ---------------- index computation ----------------
__global__ void k_idx(const float* __restrict__ p, int* __restrict__ idx) {
  int i = blockIdx.x*256 + threadIdx.x;
  if (i >= BT) return;
  float v0 = p[i*3+0], v1 = p[i*3+1], v2 = p[i*3+2];
  float v[3] = {v0, v1, v2};
  const int A0[3] = {0,0,1};
  const int A1[3] = {2,1,2};
#pragma unroll
  for (int pl = 0; pl < 3; ++pl) {
    float a = v[A0[pl]] / 1.001f + 0.5f;
    float b = v[A1[pl]] / 1.001f + 0.5f;
    a = fminf(fmaxf(a, 0.0f), 0.999f);
    b = fminf(fmaxf(b, 0.0f), 0.999f);
    int ga = (int)floorf(a * 128.0f);
    int gb = (int)floorf(b * 128.0f);
    idx[pl*BT + i] = ga + 128*gb;
  }
}

// ---------------- CSR build ----------------
__global__ void k_hist(const int* __restrict__ idx, int* __restrict__ cnt32) {
  int g = blockIdx.x*256 + threadIdx.x;
  if (g >= 3*BT) return;
  int pl = g >> 16, i = g & (BT-1);
  int b = i >> 13;
  atomicAdd(&cnt32[(pl*Bn + b)*RRn + idx[g]], 1);
}

__global__ void k_scan(const int* __restrict__ cnt32, int* __restrict__ starts,
                       int* __restrict__ cursor) {
  int seg = blockIdx.x;                 // 0..23
  const int* c = cnt32 + seg*RRn;
  int* st = starts + seg*RRn;
  int* cu = cursor + seg*RRn;
  int t = threadIdx.x;
  __shared__ int part[256];
  int base = t*64;
  int sum = 0;
#pragma unroll 8
  for (int j = 0; j < 64; ++j) sum += c[base+j];
  part[t] = sum; __syncthreads();
  for (int ofs = 1; ofs < 256; ofs <<= 1) {
    int v = (t >= ofs) ? part[t-ofs] : 0;
    __syncthreads();
    part[t] += v;
    __syncthreads();
  }
  int run = (t ? part[t-1] : 0) + seg*Tn;
#pragma unroll 8
  for (int j = 0; j < 64; ++j) { st[base+j] = run; cu[base+j] = run; run += c[base+j]; }
}

__global__ void k_fill(const int* __restrict__ idx, int* __restrict__ cursor,
                       int* __restrict__ sorted) {
  int g = blockIdx.x*256 + threadIdx.x;
  if (g >= 3*BT) return;
  int pl = g >> 16, i = g & (BT-1);
  int b = i >> 13;
  int pos = atomicAdd(&cursor[(pl*Bn + b)*RRn + idx[g]], 1);
  sorted[pos] = i;
}

// ---------------- weight prep: f32 [k][n] -> bf16 [n][k], 52 chunks of 128x128 ----
__global__ void k_prep(const float* __restrict__ bw0, const float* __restrict__ bw1,
                       const float* __restrict__ bws, const float* __restrict__ cw0,
                       const float* __restrict__ cw1, const float* __restrict__ cws,
                       const float* __restrict__ fcw, const float* __restrict__ fccw,
                       u16* __restrict__ arena) {
  int c = blockIdx.x;            // 0..51
  int s = c / 26, r = c % 26;
  const float* base;
  if (r < 10)      base = (s ? cw0 : bw0) + (size_t)(r >> 1)*32768 + (size_t)(r & 1)*16384;
  else if (r < 15) base = (s ? cw1 : bw1) + (size_t)(r - 10)*16384;
  else if (r < 25) base = (s ? cws : bws) + (size_t)((r - 15) >> 1)*32768 + (size_t)((r - 15) & 1)*16384;
  else             base = s ? fccw : fcw;
  __shared__ u16 ld[128*130];
#pragma unroll 4
  for (int it = 0; it < 64; ++it) {
    int lin = it*256 + threadIdx.x;
    int k = lin >> 7, n = lin & 127;
    ld[k*130 + n] = f2bf(base[lin]);
  }
  __syncthreads();
  u16* dst = arena + (size_t)c*16384;
#pragma unroll 4
  for (int it = 0; it < 64; ++it) {
    int lin = it*256 + threadIdx.x;
    int n = lin >> 7, k = lin & 127;
    dst[lin] = ld[k*130 + n];
  }
}

// ---------------- input projection (both streams, y = stream) ----------------
__global__ void k_proj(const float* __restrict__ p, const float* __restrict__ p2,
                       const float* __restrict__ wp, const float* __restrict__ bp,
                       const float* __restrict__ wp2, const float* __restrict__ bp2,
                       u16* __restrict__ outLo, u16* __restrict__ outHi) {
  int corr = blockIdx.y;
  int g = blockIdx.x*256 + threadIdx.x;   // BT*32
  int i = g >> 5, c8 = (g & 31) * 8;
  if (i >= BT) return;
  float a0 = p[i*3+0], a1 = p[i*3+1], a2 = p[i*3+2];
  float q0 = 0.f, q1 = 0.f, q2 = 0.f;
  if (corr) { q0 = p2[i*3+0]; q1 = p2[i*3+1]; q2 = p2[i*3+2]; }
  union { uint4 v; unsigned u[4]; } o;
#pragma unroll
  for (int k2 = 0; k2 < 4; ++k2) {
    float r[2];
#pragma unroll
    for (int t = 0; t < 2; ++t) {
      int c = c8 + k2*2 + t;
      float v = a0*wp[c] + a1*wp[256+c] + a2*wp[512+c] + bp[c];
      if (corr) v += q0*wp2[c] + q1*wp2[256+c] + q2*wp2[512+c] + bp2[c];
      r[t] = v;
    }
    o.u[k2] = (unsigned)f2bf(r[0]) | ((unsigned)f2bf(r[1]) << 16);
  }
  size_t ofs = (size_t)corr*SSTR + (size_t)i*128;
  u16* dst = (c8 < 128) ? (outLo + ofs + c8) : (outHi + ofs + (c8 - 128));
  *(uint4*)dst = o.v;
}

// ---------------- fused ResNet block (round-3 padded layout; y = stream) ----------
// x = [xA | xB] (each [BT][128] bf16), K=256.
// hidden = relu( relu(x) @ w0 + b0 )       (LDS only)
// out    = x @ ws + hidden @ w1 + b1
// FC: cout = out @ fcw + fcb               (out never hits global)
template<bool FC>
__global__ __launch_bounds__(512) void k_rb(
    const u16* __restrict__ xAb, const u16* __restrict__ xBb,
    const u16* __restrict__ arena,
    int cw00, int cw01, int cws0, int cws1, int cw1c, int cfcw,
    const float* __restrict__ b0g, const float* __restrict__ b0c,
    const float* __restrict__ b1g, const float* __restrict__ b1c,
    const float* __restrict__ fcbg, const float* __restrict__ fcbc,
    u16* __restrict__ outb)
{
  const int y = blockIdx.y;
  const u16* ar = arena + (size_t)y*26*16384;
  const u16* w00 = ar + (size_t)cw00*16384;
  const u16* w01 = ar + (size_t)cw01*16384;
  const u16* ws0 = ar + (size_t)cws0*16384;
  const u16* ws1 = ar + (size_t)cws1*16384;
  const u16* w1c = ar + (size_t)cw1c*16384;
  const u16* fcw = ar + (size_t)cfcw*16384;
  const float* b0 = y ? b0c : b0g;
  const float* b1 = y ? b1c : b1g;
  const float* fcb = y ? fcbc : fcbg;
  const u16* xA = xAb + (size_t)y*SSTR;
  const u16* xB = xBb + (size_t)y*SSTR;
  u16* outp = outb + (size_t)y*SSTR;

  __shared__ u16 xs [128*72];
  __shared__ u16 w0s[128*72];
  __shared__ u16 wss[128*72];
  __shared__ u16 hid[128*136];
  const int tid = threadIdx.x;
  const size_t row0 = (size_t)blockIdx.x * 128;
  const int l = tid & 63, w = tid >> 6;     // 8 waves, 16 rows each
  const int lm = l & 15, lg = l >> 4;
  const int trow = tid >> 2, tq = tid & 3;  // staging: 32B/thread/buffer

  f4v acc_h[8], acc_s[8];
#pragma unroll
  for (int j = 0; j < 8; ++j) { acc_h[j] = (f4v){0,0,0,0}; acc_s[j] = (f4v){0,0,0,0}; }

  const u16* pa  = xs  + (w*16 + lm)*72 + lg*8;
  const u16* pbh = w0s + lm*72 + lg*8;
  const u16* pbs = wss + lm*72 + lg*8;

#pragma unroll 1
  for (int kc = 0; kc < 4; ++kc) {
    const u16* xsrc  = (kc < 2) ? xA  : xB;
    const u16* w0src = (kc < 2) ? w00 : w01;
    const u16* wssrc = (kc < 2) ? ws0 : ws1;
    const int k0 = (kc & 1) * 64;
    __syncthreads();
    {
      const u16* s1 = xsrc + (row0 + trow)*128 + k0 + tq*16;
      uint4* d1 = (uint4*)(xs + trow*72 + tq*16);
      d1[0] = ((const uint4*)s1)[0]; d1[1] = ((const uint4*)s1)[1];
      const u16* s2 = w0src + trow*128 + k0 + tq*16;
      uint4* d2 = (uint4*)(w0s + trow*72 + tq*16);
      d2[0] = ((const uint4*)s2)[0]; d2[1] = ((const uint4*)s2)[1];
      const u16* s3 = wssrc + trow*128 + k0 + tq*16;
      uint4* d3 = (uint4*)(wss + trow*72 + tq*16);
      d3[0] = ((const uint4*)s3)[0]; d3[1] = ((const uint4*)s3)[1];
    }
    __syncthreads();
#pragma unroll
    for (int kk = 0; kk < 2; ++kk) {
      s8v a  = *(const s8v*)(pa + kk*32);
      s8v ar2 = relu8(a);
#pragma unroll
      for (int nj = 0; nj < 8; ++nj) {
        s8v bh = *(const s8v*)(pbh + nj*16*72 + kk*32);
        acc_h[nj] = __builtin_amdgcn_mfma_f32_16x16x32_bf16(ar2, bh, acc_h[nj], 0, 0, 0);
      }
#pragma unroll
      for (int nj = 0; nj < 8; ++nj) {
        s8v bs = *(const s8v*)(pbs + nj*16*72 + kk*32);
        acc_s[nj] = __builtin_amdgcn_mfma_f32_16x16x32_bf16(a, bs, acc_s[nj], 0, 0, 0);
      }
    }
  }
  __syncthreads();   // all pass-1 LDS reads done
  // stage w1 halves; write hidden = relu(acc_h + b0)
  {
    const u16* s1 = w1c + trow*128 + tq*16;
    uint4* d1 = (uint4*)(w0s + trow*72 + tq*16);
    d1[0] = ((const uint4*)s1)[0]; d1[1] = ((const uint4*)s1)[1];
    const u16* s2 = w1c + trow*128 + 64 + tq*16;
    uint4* d2 = (uint4*)(wss + trow*72 + tq*16);
    d2[0] = ((const uint4*)s2)[0]; d2[1] = ((const uint4*)s2)[1];
#pragma unroll
    for (int nj = 0; nj < 8; ++nj) {
      const int col = nj*16 + lm;
      const float bv = b0[col];
#pragma unroll
      for (int r = 0; r < 4; ++r) {
        int row = w*16 + lg*4 + r;
        hid[row*136 + col] = f2bf(fmaxf(acc_h[nj][r] + bv, 0.0f));
      }
    }
  }
  __syncthreads();
  // pass 2: acc_s += hidden @ w1
  {
    const u16* pah = hid + (w*16 + lm)*136 + lg*8;
#pragma unroll
    for (int kk = 0; kk < 4; ++kk) {
      s8v a = *(const s8v*)(pah + kk*32);
      const u16* pb = ((kk < 2) ? w0s : wss) + lm*72 + lg*8 + (kk & 1)*32;
#pragma unroll
      for (int nj = 0; nj < 8; ++nj) {
        s8v bb = *(const s8v*)(pb + nj*16*72);
        acc_s[nj] = __builtin_amdgcn_mfma_f32_16x16x32_bf16(a, bb, acc_s[nj], 0, 0, 0);
      }
    }
  }
  if (!FC) {
#pragma unroll
    for (int nj = 0; nj < 8; ++nj) {
      const int col = nj*16 + lm;
      const float bv = b1[col];
#pragma unroll
      for (int r = 0; r < 4; ++r) {
        int row = w*16 + lg*4 + r;
        outp[(row0 + row)*128 + col] = f2bf(acc_s[nj][r] + bv);
      }
    }
  } else {
    __syncthreads();   // pass-2 reads of hid/w0s/wss done
#pragma unroll
    for (int nj = 0; nj < 8; ++nj) {
      const int col = nj*16 + lm;
      const float bv = b1[col];
#pragma unroll
      for (int r = 0; r < 4; ++r) {
        int row = w*16 + lg*4 + r;
        hid[row*136 + col] = f2bf(acc_s[nj][r] + bv);
      }
    }
    const u16* s1 = fcw + trow*128 + tq*16;
    uint4* d1 = (uint4*)(w0s + trow*72 + tq*16);
    d1[0] = ((const uint4*)s1)[0]; d1[1] = ((const uint4*)s1)[1];
    const u16* s2 = fcw + trow*128 + 64 + tq*16;
    uint4* d2 = (uint4*)(wss + trow*72 + tq*16);
    d2[0] = ((const uint4*)s2)[0]; d2[1] = ((const uint4*)s2)[1];
    __syncthreads();
    f4v accf[8];
#pragma unroll
    for (int j = 0; j < 8; ++j) accf[j] = (f4v){0,0,0,0};
    const u16* pah = hid + (w*16 + lm)*136 + lg*8;
#pragma unroll
    for (int kk = 0; kk < 4; ++kk) {
      s8v a = *(const s8v*)(pah + kk*32);
      const u16* pb = ((kk < 2) ? w0s : wss) + lm*72 + lg*8 + (kk & 1)*32;
#pragma unroll
      for (int nj = 0; nj < 8; ++nj) {
        s8v bb = *(const s8v*)(pb + nj*16*72);
        accf[nj] = __builtin_amdgcn_mfma_f32_16x16x32_bf16(a, bb, accf[nj], 0, 0, 0);
      }
    }
#pragma unroll
    for (int nj = 0; nj < 8; ++nj) {
      const int col = nj*16 + lm;
      const float bv = fcb[col];
#pragma unroll
      for (int r = 0; r < 4; ++r) {
        int row = w*16 + lg*4 + r;
        outp[(row0 + row)*128 + col] = f2bf(accf[nj][r] + bv);
      }
    }
  }
}

// ---------------- CSR pooling (y = stream) ----------------
__global__ void k_pool(const int* __restrict__ idx, const int* __restrict__ starts,
                       const int* __restrict__ cnt32, const int* __restrict__ sorted,
                       const u16* __restrict__ netb, u16* __restrict__ pooledb) {
  const u16* net = netb + (size_t)blockIdx.y*SSTR;
  u16* pooled = pooledb + (size_t)blockIdx.y*SSTR;
  int g = blockIdx.x*256 + threadIdx.x;    // BT*16
  int sl = g & 15;
  int i = g >> 4;
  if (i >= BT) return;
  int b = i >> 13;
  float acc[8];
#pragma unroll
  for (int k = 0; k < 8; ++k) acc[k] = 0.0f;
#pragma unroll
  for (int pl = 0; pl < 3; ++pl) {
    int seg = (pl*Bn + b)*RRn + idx[pl*BT + i];
    int s = starts[seg];
    int e = s + cnt32[seg];
    float mx[8];
#pragma unroll
    for (int k = 0; k < 8; ++k) mx[k] = -3.0e38f;
    for (int j = s; j < e; ++j) {
      int jj = sorted[j];
      uint4 v = *(const uint4*)(net + (size_t)jj*128 + sl*8);
      float lo, hi;
      upk(v.x, lo, hi); mx[0] = fmaxf(mx[0], lo); mx[1] = fmaxf(mx[1], hi);
      upk(v.y, lo, hi); mx[2] = fmaxf(mx[2], lo); mx[3] = fmaxf(mx[3], hi);
      upk(v.z, lo, hi); mx[4] = fmaxf(mx[4], lo); mx[5] = fmaxf(mx[5], hi);
      upk(v.w, lo, hi); mx[6] = fmaxf(mx[6], lo); mx[7] = fmaxf(mx[7], hi);
    }
#pragma unroll
    for (int k = 0; k < 8; ++k) acc[k] += mx[k];
  }
  union { uint4 v; unsigned u[4]; } o;
#pragma unroll
  for (int k = 0; k < 4; ++k)
    o.u[k] = (unsigned)f2bf(acc[2*k]) | ((unsigned)f2bf(acc[2*k+1]) << 16);
  *(uint4*)(pooled + (size_t)i*128 + sl*8) = o.v;
}

// ---------------- scatter-mean, lane-per-bin, coalesced full-line writes -------
// Covers all 6 planes (both streams); empty bins write 0. No memset needed.
__global__ __launch_bounds__(256) void k_mean(
    const int* __restrict__ starts, const int* __restrict__ cnt32,
    const int* __restrict__ sorted, const u16* __restrict__ cbufb,
    float* __restrict__ out) {
  int W = blockIdx.x*4 + (threadIdx.x >> 6);   // 12288 waves
  int lane = threadIdx.x & 63;
  int grp = W & 255;
  int b = (W >> 8) & 7;
  int plq = W >> 11;            // 0..5 output plane
  int ss = plq / 3, pl = plq - 3*ss;
  int bin = grp*64 + lane;
  int seg = (pl*Bn + b)*RRn + bin;
  int c = cnt32[seg];
  int s0 = starts[seg];
  float inv = (c > 0) ? 1.0f/(float)c : 0.0f;
  const u16* cb = cbufb + (size_t)ss*SSTR;
  size_t obase = ((size_t)(plq*Bn + b)*Hn)*RRn + bin;
#pragma unroll 1
  for (int half = 0; half < 2; ++half) {
    float sum[64];
#pragma unroll
    for (int k = 0; k < 64; ++k) sum[k] = 0.f;
    for (int j = 0; j < c; ++j) {
      int jj = sorted[s0 + j];
      const uint4* r = (const uint4*)(cb + (size_t)jj*128 + half*64);
#pragma unroll
      for (int k = 0; k < 8; ++k) {
        uint4 q = r[k];
        float lo, hi;
        upk(q.x, lo, hi); sum[k*8+0] += lo; sum[k*8+1] += hi;
        upk(q.y, lo, hi); sum[k*8+2] += lo; sum[k*8+3] += hi;
        upk(q.z, lo, hi); sum[k*8+4] += lo; sum[k*8+5] += hi;
        upk(q.w, lo, hi); sum[k*8+6] += lo; sum[k*8+7] += hi;
      }
    }
#pragma unroll
    for (int k = 0; k < 64; ++k)
      out[obase + (size_t)(half*64 + k)*RRn] = sum[k]*inv;
  }
}

// ---------------- host ----------------
extern "C" void kernel_launch(void* const* d_in, const int* in_sizes, int n_in,
                              void* d_out_v, int out_size, void* d_ws, size_t ws_size,
                              hipStream_t stream) {
  const float* p    = (const float*)d_in[0];
  const float* p2   = (const float*)d_in[1];
  const float* wp   = (const float*)d_in[2];
  const float* bp   = (const float*)d_in[3];
  const float* wp2  = (const float*)d_in[4];
  const float* bp2  = (const float*)d_in[5];
  const float* bw0  = (const float*)d_in[6];
  const float* bb0  = (const float*)d_in[7];
  const float* bw1  = (const float*)d_in[8];
  const float* bb1  = (const float*)d_in[9];
  const float* bws  = (const float*)d_in[10];
  const float* cw0  = (const float*)d_in[11];
  const float* cb0  = (const float*)d_in[12];
  const float* cw1  = (const float*)d_in[13];
  const float* cb1  = (const float*)d_in[14];
  const float* cws  = (const float*)d_in[15];
  const float* fcw  = (const float*)d_in[16];
  const float* fcb  = (const float*)d_in[17];
  const float* fccw = (const float*)d_in[18];
  const float* fccb = (const float*)d_in[19];
  float* out = (float*)d_out_v;

  size_t off = 0;
  auto alloc = [&](size_t bytes) -> char* {
    char* r = (char*)d_ws + off;
    off += (bytes + 255) & ~(size_t)255;
    return r;
  };
  int* idx    = (int*)alloc((size_t)3*BT*4);
  int* cnt32  = (int*)alloc((size_t)3*Bn*RRn*4);
  int* starts = (int*)alloc((size_t)3*Bn*RRn*4);
  int* cursor = (int*)alloc((size_t)3*Bn*RRn*4);
  int* sorted = (int*)alloc((size_t)3*BT*4);
  u16* arena  = (u16*)alloc((size_t)52*16384*2);
  u16* buf0   = (u16*)alloc(2*SSTR*2);   // [stream][BT][128]
  u16* buf1   = (u16*)alloc(2*SSTR*2);
  u16* bufP   = (u16*)alloc(2*SSTR*2);
  u16* cbuf   = (u16*)alloc(2*SSTR*2);
  if (off > ws_size) return;

  hipMemsetAsync(cnt32, 0, (size_t)3*Bn*RRn*4, stream);
  k_prep<<<52, 256, 0, stream>>>(bw0, bw1, bws, cw0, cw1, cws, fcw, fccw, arena);
  k_idx <<<BT/256, 256, 0, stream>>>(p, idx);
  k_hist<<<(3*BT)/256, 256, 0, stream>>>(idx, cnt32);
  k_scan<<<24, 256, 0, stream>>>(cnt32, starts, cursor);
  k_fill<<<(3*BT)/256, 256, 0, stream>>>(idx, cursor, sorted);

  k_proj<<<dim3((BT*32)/256, 2), 256, 0, stream>>>(p, p2, wp, bp, wp2, bp2, buf0, bufP);

  // block 0: x = [buf0 | bufP]
  k_rb<false><<<dim3(BT/128, 2), 512, 0, stream>>>(
      buf0, bufP, arena, 0, 1, 15, 16, 10, 25,
      bb0, cb0, bb1, cb1, nullptr, nullptr, buf1);
  u16* net = buf1; u16* other = buf0;
  for (int blk = 1; blk < 4; ++blk) {
    k_pool<<<dim3((BT*16)/256, 2), 256, 0, stream>>>(idx, starts, cnt32, sorted, net, bufP);
    k_rb<false><<<dim3(BT/128, 2), 512, 0, stream>>>(
        net, bufP, arena, 2*blk, 2*blk+1, 15+2*blk, 16+2*blk, 10+blk, 25,
        bb0 + blk*128, cb0 + blk*128, bb1 + blk*128, cb1 + blk*128,
        nullptr, nullptr, other);
    u16* t = net; net = other; other = t;
  }
  // block 4 fused with final fc -> cbuf
  k_pool<<<dim3((BT*16)/256, 2), 256, 0, stream>>>(idx, starts, cnt32, sorted, net, bufP);
  k_rb<true><<<dim3(BT/128, 2), 512, 0, stream>>>(
      net, bufP, arena, 8, 9, 23, 24, 14, 25,
      bb0 + 4*128, cb0 + 4*128, bb1 + 4*128, cb1 + 4*128, fcb, fccb, cbuf);

  // scatter-mean: all 6 planes, full coverage (zeros for empty bins)
  k_mean<<<3072, 256, 0, stream>>>(starts, cnt32, sorted, cbuf, out);
}

// Round 6
// 609.111 us; speedup vs baseline: 1.7578x; 1.5024x over previous
//
#include <hip/hip_runtime.h>
#include <cstdint>
#include <cstddef>

#define Bn 8
#define Tn 8192
#define BT (Bn*Tn)      // 65536 points
#define Hn 128
#define RRn 16384       // 128*128 bins per plane per batch

typedef unsigned short u16;
typedef __attribute__((ext_vector_type(8))) short s8v;   // 8 bf16 (4 VGPRs)
typedef __attribute__((ext_vector_type(4))) float f4v;   // 4 f32 acc

#define SSTR ((size_t)BT*128)   // per-stream activation stride (elements)

__device__ __forceinline__ u16 f2bf(float f) {
  unsigned u = __float_as_uint(f);
  unsigned r = (u + 0x7FFF + ((u >> 16) & 1)) >> 16;   // RNE
  return (u16)r;
}
__device__ __forceinline__ unsigned pack2(float a, float b) {
  return (unsigned)f2bf(a) | ((unsigned)f2bf(b) << 16);
}

__device__ __forceinline__ s8v relu8(s8v a) {
  union { s8v s; unsigned u[4]; } x; x.s = a;
#pragma unroll
  for (int k = 0; k < 4; ++k) {
    unsigned m = ((x.u[k] & 0x80008000u) >> 15) * 0xFFFFu;
    x.u[k] &= ~m;
  }
  return x.s;
}

__device__ __forceinline__ void upk(unsigned u, float& lo, float& hi) {
  lo = __uint_as_float(u << 16);
  hi = __uint_as_float(u & 0xFFFF0000u);
}

// ---------------- index computation ----------------
__global__ void k_idx(const float* __restrict__ p, int* __restrict__ idx) {
  int i = blockIdx.x*256 + threadIdx.x;
  if (i >= BT) return;
  float v0 = p[i*3+0], v1 = p[i*3+1], v2 = p[i*3+2];
  float v[3] = {v0, v1, v2};
  const int A0[3] = {0,0,1};
  const int A1[3] = {2,1,2};
#pragma unroll
  for (int pl = 0; pl < 3; ++pl) {
    float a = v[A0[pl]] / 1.001f + 0.5f;
    float b = v[A1[pl]] / 1.001f + 0.5f;
    a = fminf(fmaxf(a, 0.0f), 0.999f);
    b = fminf(fmaxf(b, 0.0f), 0.999f);
    int ga = (int)floorf(a * 128.0f);
    int gb = (int)floorf(b * 128.0f);
    idx[pl*BT + i] = ga + 128*gb;
  }
}

// ---------------- CSR build ----------------
__global__ void k_hist(const int* __restrict__ idx, int* __restrict__ cnt32) {
  int g = blockIdx.x*256 + threadIdx.x;
  if (g >= 3*BT) return;
  int pl = g >> 16, i = g & (BT-1);
  int b = i >> 13;
  atomicAdd(&cnt32[(pl*Bn + b)*RRn + idx[g]], 1);
}

__global__ void k_scan(const int* __restrict__ cnt32, int* __restrict__ starts,
                       int* __restrict__ cursor) {
  int seg = blockIdx.x;                 // 0..23
  const int* c = cnt32 + seg*RRn;
  int* st = starts + seg*RRn;
  int* cu = cursor + seg*RRn;
  int t = threadIdx.x;
  __shared__ int part[256];
  int base = t*64;
  int sum = 0;
#pragma unroll 8
  for (int j = 0; j < 64; ++j) sum += c[base+j];
  part[t] = sum; __syncthreads();
  for (int ofs = 1; ofs < 256; ofs <<= 1) {
    int v = (t >= ofs) ? part[t-ofs] : 0;
    __syncthreads();
    part[t] += v;
    __syncthreads();
  }
  int run = (t ? part[t-1] : 0) + seg*Tn;
#pragma unroll 8
  for (int j = 0; j < 64; ++j) { st[base+j] = run; cu[base+j] = run; run += c[base+j]; }
}

__global__ void k_fill(const int* __restrict__ idx, int* __restrict__ cursor,
                       int* __restrict__ sorted) {
  int g = blockIdx.x*256 + threadIdx.x;
  if (g >= 3*BT) return;
  int pl = g >> 16, i = g & (BT-1);
  int b = i >> 13;
  int pos = atomicAdd(&cursor[(pl*Bn + b)*RRn + idx[g]], 1);
  sorted[pos] = i;
}

// ---------------- weight prep: f32 [k][n] -> bf16 [n][k], 52 chunks of 128x128 ----
__global__ void k_prep(const float* __restrict__ bw0, const float* __restrict__ bw1,
                       const float* __restrict__ bws, const float* __restrict__ cw0,
                       const float* __restrict__ cw1, const float* __restrict__ cws,
                       const float* __restrict__ fcw, const float* __restrict__ fccw,
                       u16* __restrict__ arena) {
  int c = blockIdx.x;            // 0..51
  int s = c / 26, r = c % 26;
  const float* base;
  if (r < 10)      base = (s ? cw0 : bw0) + (size_t)(r >> 1)*32768 + (size_t)(r & 1)*16384;
  else if (r < 15) base = (s ? cw1 : bw1) + (size_t)(r - 10)*16384;
  else if (r < 25) base = (s ? cws : bws) + (size_t)((r - 15) >> 1)*32768 + (size_t)((r - 15) & 1)*16384;
  else             base = s ? fccw : fcw;
  __shared__ u16 ld[128*130];
#pragma unroll 4
  for (int it = 0; it < 64; ++it) {
    int lin = it*256 + threadIdx.x;
    int k = lin >> 7, n = lin & 127;
    ld[k*130 + n] = f2bf(base[lin]);
  }
  __syncthreads();
  u16* dst = arena + (size_t)c*16384;
#pragma unroll 4
  for (int it = 0; it < 64; ++it) {
    int lin = it*256 + threadIdx.x;
    int n = lin >> 7, k = lin & 127;
    dst[lin] = ld[k*130 + n];
  }
}

// ---------------- fused ResNet block (y = stream) ----------------
// MODE 0: x = [xA|xB] from global.  MODE 1: x = projection computed in staging
// (block 0; eliminates k_proj).     MODE 2: like 0 plus fused final FC.
// hidden = relu( relu(x) @ w0 + b0 )   (LDS only)
// out    = x @ ws + hidden @ w1 + b1   [; cout = out @ fcw + fcb in MODE 2]
template<int MODE>
__global__ __launch_bounds__(512) void k_rb(
    const u16* __restrict__ xAb, const u16* __restrict__ xBb,
    const float* __restrict__ p, const float* __restrict__ p2,
    const float* __restrict__ wp, const float* __restrict__ bp,
    const float* __restrict__ wp2, const float* __restrict__ bp2,
    const u16* __restrict__ arena,
    int cw00, int cw01, int cws0, int cws1, int cw1c, int cfcw,
    const float* __restrict__ b0g, const float* __restrict__ b0c,
    const float* __restrict__ b1g, const float* __restrict__ b1c,
    const float* __restrict__ fcbg, const float* __restrict__ fcbc,
    u16* __restrict__ outb)
{
  const int y = blockIdx.y;
  const u16* ar = arena + (size_t)y*26*16384;
  const u16* w00 = ar + (size_t)cw00*16384;
  const u16* w01 = ar + (size_t)cw01*16384;
  const u16* ws0 = ar + (size_t)cws0*16384;
  const u16* ws1 = ar + (size_t)cws1*16384;
  const u16* w1c = ar + (size_t)cw1c*16384;
  const u16* fcw = ar + (size_t)cfcw*16384;
  const float* b0 = y ? b0c : b0g;
  const float* b1 = y ? b1c : b1g;
  const float* fcb = y ? fcbc : fcbg;
  const u16* xA = xAb + (size_t)y*SSTR;
  const u16* xB = xBb + (size_t)y*SSTR;
  u16* outp = outb + (size_t)y*SSTR;

  __shared__ u16 xs [128*72];
  __shared__ u16 w0s[128*72];
  __shared__ u16 wss[128*72];
  __shared__ u16 hid[128*136];
  const int tid = threadIdx.x;
  const size_t row0 = (size_t)blockIdx.x * 128;
  const int l = tid & 63, w = tid >> 6;     // 8 waves, 16 rows each
  const int lm = l & 15, lg = l >> 4;
  const int trow = tid >> 2, tq = tid & 3;  // staging: 32B/thread/buffer

  f4v acc_h[8], acc_s[8];
#pragma unroll
  for (int j = 0; j < 8; ++j) { acc_h[j] = (f4v){0,0,0,0}; acc_s[j] = (f4v){0,0,0,0}; }

  // projection inputs (MODE 1 only)
  float pa0=0.f, pa1=0.f, pa2=0.f, pq0=0.f, pq1=0.f, pq2=0.f;
  if (MODE == 1) {
    int rr = (int)row0 + trow;
    pa0 = p[rr*3+0]; pa1 = p[rr*3+1]; pa2 = p[rr*3+2];
    if (y) { pq0 = p2[rr*3+0]; pq1 = p2[rr*3+1]; pq2 = p2[rr*3+2]; }
  }

  const u16* pa  = xs  + (w*16 + lm)*72 + lg*8;
  const u16* pbh = w0s + lm*72 + lg*8;
  const u16* pbs = wss + lm*72 + lg*8;

#pragma unroll 1
  for (int kc = 0; kc < 4; ++kc) {
    const u16* xsrc  = (kc < 2) ? xA  : xB;
    const u16* w0src = (kc < 2) ? w00 : w01;
    const u16* wssrc = (kc < 2) ? ws0 : ws1;
    const int k0 = (kc & 1) * 64;
    __syncthreads();
    {
      if (MODE == 1) {
        // compute 16 projection channels: c0 .. c0+15
        const int c0 = (kc >> 1)*128 + k0 + tq*16;
        unsigned tmp[8];
#pragma unroll
        for (int q = 0; q < 4; ++q) {
          float4 w0v = *(const float4*)(wp + c0 + q*4);
          float4 w1v = *(const float4*)(wp + 256 + c0 + q*4);
          float4 w2v = *(const float4*)(wp + 512 + c0 + q*4);
          float4 bbv = *(const float4*)(bp + c0 + q*4);
          float v0 = pa0*w0v.x + pa1*w1v.x + pa2*w2v.x + bbv.x;
          float v1 = pa0*w0v.y + pa1*w1v.y + pa2*w2v.y + bbv.y;
          float v2 = pa0*w0v.z + pa1*w1v.z + pa2*w2v.z + bbv.z;
          float v3 = pa0*w0v.w + pa1*w1v.w + pa2*w2v.w + bbv.w;
          if (y) {
            float4 u0 = *(const float4*)(wp2 + c0 + q*4);
            float4 u1 = *(const float4*)(wp2 + 256 + c0 + q*4);
            float4 u2 = *(const float4*)(wp2 + 512 + c0 + q*4);
            float4 b2 = *(const float4*)(bp2 + c0 + q*4);
            v0 += pq0*u0.x + pq1*u1.x + pq2*u2.x + b2.x;
            v1 += pq0*u0.y + pq1*u1.y + pq2*u2.y + b2.y;
            v2 += pq0*u0.z + pq1*u1.z + pq2*u2.z + b2.z;
            v3 += pq0*u0.w + pq1*u1.w + pq2*u2.w + b2.w;
          }
          tmp[q*2]   = pack2(v0, v1);
          tmp[q*2+1] = pack2(v2, v3);
        }
        uint4* d1 = (uint4*)(xs + trow*72 + tq*16);
        d1[0] = make_uint4(tmp[0], tmp[1], tmp[2], tmp[3]);
        d1[1] = make_uint4(tmp[4], tmp[5], tmp[6], tmp[7]);
      } else {
        const u16* s1 = xsrc + (row0 + trow)*128 + k0 + tq*16;
        uint4* d1 = (uint4*)(xs + trow*72 + tq*16);
        d1[0] = ((const uint4*)s1)[0]; d1[1] = ((const uint4*)s1)[1];
      }
      const u16* s2 = w0src + trow*128 + k0 + tq*16;
      uint4* d2 = (uint4*)(w0s + trow*72 + tq*16);
      d2[0] = ((const uint4*)s2)[0]; d2[1] = ((const uint4*)s2)[1];
      const u16* s3 = wssrc + trow*128 + k0 + tq*16;
      uint4* d3 = (uint4*)(wss + trow*72 + tq*16);
      d3[0] = ((const uint4*)s3)[0]; d3[1] = ((const uint4*)s3)[1];
    }
    __syncthreads();
#pragma unroll
    for (int kk = 0; kk < 2; ++kk) {
      s8v a  = *(const s8v*)(pa + kk*32);
      s8v ar2 = relu8(a);
#pragma unroll
      for (int nj = 0; nj < 8; ++nj) {
        s8v bh = *(const s8v*)(pbh + nj*16*72 + kk*32);
        acc_h[nj] = __builtin_amdgcn_mfma_f32_16x16x32_bf16(ar2, bh, acc_h[nj], 0, 0, 0);
      }
#pragma unroll
      for (int nj = 0; nj < 8; ++nj) {
        s8v bs = *(const s8v*)(pbs + nj*16*72 + kk*32);
        acc_s[nj] = __builtin_amdgcn_mfma_f32_16x16x32_bf16(a, bs, acc_s[nj], 0, 0, 0);
      }
    }
  }
  __syncthreads();   // all pass-1 LDS reads done
  // stage w1 halves; write hidden = relu(acc_h + b0)
  {
    const u16* s1 = w1c + trow*128 + tq*16;
    uint4* d1 = (uint4*)(w0s + trow*72 + tq*16);
    d1[0] = ((const uint4*)s1)[0]; d1[1] = ((const uint4*)s1)[1];
    const u16* s2 = w1c + trow*128 + 64 + tq*16;
    uint4* d2 = (uint4*)(wss + trow*72 + tq*16);
    d2[0] = ((const uint4*)s2)[0]; d2[1] = ((const uint4*)s2)[1];
#pragma unroll
    for (int nj = 0; nj < 8; ++nj) {
      const int col = nj*16 + lm;
      const float bv = b0[col];
#pragma unroll
      for (int r = 0; r < 4; ++r) {
        int row = w*16 + lg*4 + r;
        hid[row*136 + col] = f2bf(fmaxf(acc_h[nj][r] + bv, 0.0f));
      }
    }
  }
  __syncthreads();
  // pass 2: acc_s += hidden @ w1
  {
    const u16* pah = hid + (w*16 + lm)*136 + lg*8;
#pragma unroll
    for (int kk = 0; kk < 4; ++kk) {
      s8v a = *(const s8v*)(pah + kk*32);
      const u16* pb = ((kk < 2) ? w0s : wss) + lm*72 + lg*8 + (kk & 1)*32;
#pragma unroll
      for (int nj = 0; nj < 8; ++nj) {
        s8v bb = *(const s8v*)(pb + nj*16*72);
        acc_s[nj] = __builtin_amdgcn_mfma_f32_16x16x32_bf16(a, bb, acc_s[nj], 0, 0, 0);
      }
    }
  }
  if (MODE != 2) {
#pragma unroll
    for (int nj = 0; nj < 8; ++nj) {
      const int col = nj*16 + lm;
      const float bv = b1[col];
#pragma unroll
      for (int r = 0; r < 4; ++r) {
        int row = w*16 + lg*4 + r;
        outp[(row0 + row)*128 + col] = f2bf(acc_s[nj][r] + bv);
      }
    }
  } else {
    __syncthreads();   // pass-2 reads of hid/w0s/wss done
#pragma unroll
    for (int nj = 0; nj < 8; ++nj) {
      const int col = nj*16 + lm;
      const float bv = b1[col];
#pragma unroll
      for (int r = 0; r < 4; ++r) {
        int row = w*16 + lg*4 + r;
        hid[row*136 + col] = f2bf(acc_s[nj][r] + bv);
      }
    }
    const u16* s1 = fcw + trow*128 + tq*16;
    uint4* d1 = (uint4*)(w0s + trow*72 + tq*16);
    d1[0] = ((const uint4*)s1)[0]; d1[1] = ((const uint4*)s1)[1];
    const u16* s2 = fcw + trow*128 + 64 + tq*16;
    uint4* d2 = (uint4*)(wss + trow*72 + tq*16);
    d2[0] = ((const uint4*)s2)[0]; d2[1] = ((const uint4*)s2)[1];
    __syncthreads();
    f4v accf[8];
#pragma unroll
    for (int j = 0; j < 8; ++j) accf[j] = (f4v){0,0,0,0};
    const u16* pah = hid + (w*16 + lm)*136 + lg*8;
#pragma unroll
    for (int kk = 0; kk < 4; ++kk) {
      s8v a = *(const s8v*)(pah + kk*32);
      const u16* pb = ((kk < 2) ? w0s : wss) + lm*72 + lg*8 + (kk & 1)*32;
#pragma unroll
      for (int nj = 0; nj < 8; ++nj) {
        s8v bb = *(const s8v*)(pb + nj*16*72);
        accf[nj] = __builtin_amdgcn_mfma_f32_16x16x32_bf16(a, bb, accf[nj], 0, 0, 0);
      }
    }
#pragma unroll
    for (int nj = 0; nj < 8; ++nj) {
      const int col = nj*16 + lm;
      const float bv = fcb[col];
#pragma unroll
      for (int r = 0; r < 4; ++r) {
        int row = w*16 + lg*4 + r;
        outp[(row0 + row)*128 + col] = f2bf(accf[nj][r] + bv);
      }
    }
  }
}

// ---------------- CSR pooling (y = stream) ----------------
__global__ void k_pool(const int* __restrict__ idx, const int* __restrict__ starts,
                       const int* __restrict__ cnt32, const int* __restrict__ sorted,
                       const u16* __restrict__ netb, u16* __restrict__ pooledb) {
  const u16* net = netb + (size_t)blockIdx.y*SSTR;
  u16* pooled = pooledb + (size_t)blockIdx.y*SSTR;
  int g = blockIdx.x*256 + threadIdx.x;    // BT*16
  int sl = g & 15;
  int i = g >> 4;
  if (i >= BT) return;
  int b = i >> 13;
  float acc[8];
#pragma unroll
  for (int k = 0; k < 8; ++k) acc[k] = 0.0f;
#pragma unroll
  for (int pl = 0; pl < 3; ++pl) {
    int seg = (pl*Bn + b)*RRn + idx[pl*BT + i];
    int s = starts[seg];
    int e = s + cnt32[seg];
    float mx[8];
#pragma unroll
    for (int k = 0; k < 8; ++k) mx[k] = -3.0e38f;
    for (int j = s; j < e; ++j) {
      int jj = sorted[j];
      uint4 v = *(const uint4*)(net + (size_t)jj*128 + sl*8);
      float lo, hi;
      upk(v.x, lo, hi); mx[0] = fmaxf(mx[0], lo); mx[1] = fmaxf(mx[1], hi);
      upk(v.y, lo, hi); mx[2] = fmaxf(mx[2], lo); mx[3] = fmaxf(mx[3], hi);
      upk(v.z, lo, hi); mx[4] = fmaxf(mx[4], lo); mx[5] = fmaxf(mx[5], hi);
      upk(v.w, lo, hi); mx[6] = fmaxf(mx[6], lo); mx[7] = fmaxf(mx[7], hi);
    }
#pragma unroll
    for (int k = 0; k < 8; ++k) acc[k] += mx[k];
  }
  union { uint4 v; unsigned u[4]; } o;
#pragma unroll
  for (int k = 0; k < 4; ++k)
    o.u[k] = (unsigned)f2bf(acc[2*k]) | ((unsigned)f2bf(acc[2*k+1]) << 16);
  *(uint4*)(pooled + (size_t)i*128 + sl*8) = o.v;
}

// ---------------- scatter-mean, lane-per-bin, coalesced full-line writes -------
__global__ __launch_bounds__(256) void k_mean(
    const int* __restrict__ starts, const int* __restrict__ cnt32,
    const int* __restrict__ sorted, const u16* __restrict__ cbufb,
    float* __restrict__ out) {
  int W = blockIdx.x*4 + (threadIdx.x >> 6);   // 12288 waves
  int lane = threadIdx.x & 63;
  int grp = W & 255;
  int b = (W >> 8) & 7;
  int plq = W >> 11;            // 0..5 output plane
  int ss = plq / 3, pl = plq - 3*ss;
  int bin = grp*64 + lane;
  int seg = (pl*Bn + b)*RRn + bin;
  int c = cnt32[seg];
  int s0 = starts[seg];
  float inv = (c > 0) ? 1.0f/(float)c : 0.0f;
  const u16* cb = cbufb + (size_t)ss*SSTR;
  size_t obase = ((size_t)(plq*Bn + b)*Hn)*RRn + bin;
#pragma unroll 1
  for (int half = 0; half < 2; ++half) {
    float sum[64];
#pragma unroll
    for (int k = 0; k < 64; ++k) sum[k] = 0.f;
    for (int j = 0; j < c; ++j) {
      int jj = sorted[s0 + j];
      const uint4* r = (const uint4*)(cb + (size_t)jj*128 + half*64);
#pragma unroll
      for (int k = 0; k < 8; ++k) {
        uint4 q = r[k];
        float lo, hi;
        upk(q.x, lo, hi); sum[k*8+0] += lo; sum[k*8+1] += hi;
        upk(q.y, lo, hi); sum[k*8+2] += lo; sum[k*8+3] += hi;
        upk(q.z, lo, hi); sum[k*8+4] += lo; sum[k*8+5] += hi;
        upk(q.w, lo, hi); sum[k*8+6] += lo; sum[k*8+7] += hi;
      }
    }
#pragma unroll
    for (int k = 0; k < 64; ++k)
      out[obase + (size_t)(half*64 + k)*RRn] = sum[k]*inv;
  }
}

// ---------------- host ----------------
extern "C" void kernel_launch(void* const* d_in, const int* in_sizes, int n_in,
                              void* d_out_v, int out_size, void* d_ws, size_t ws_size,
                              hipStream_t stream) {
  const float* p    = (const float*)d_in[0];
  const float* p2   = (const float*)d_in[1];
  const float* wp   = (const float*)d_in[2];
  const float* bp   = (const float*)d_in[3];
  const float* wp2  = (const float*)d_in[4];
  const float* bp2  = (const float*)d_in[5];
  const float* bw0  = (const float*)d_in[6];
  const float* bb0  = (const float*)d_in[7];
  const float* bw1  = (const float*)d_in[8];
  const float* bb1  = (const float*)d_in[9];
  const float* bws  = (const float*)d_in[10];
  const float* cw0  = (const float*)d_in[11];
  const float* cb0  = (const float*)d_in[12];
  const float* cw1  = (const float*)d_in[13];
  const float* cb1  = (const float*)d_in[14];
  const float* cws  = (const float*)d_in[15];
  const float* fcw  = (const float*)d_in[16];
  const float* fcb  = (const float*)d_in[17];
  const float* fccw = (const float*)d_in[18];
  const float* fccb = (const float*)d_in[19];
  float* out = (float*)d_out_v;

  size_t off = 0;
  auto alloc = [&](size_t bytes) -> char* {
    char* r = (char*)d_ws + off;
    off += (bytes + 255) & ~(size_t)255;
    return r;
  };
  int* idx    = (int*)alloc((size_t)3*BT*4);
  int* cnt32  = (int*)alloc((size_t)3*Bn*RRn*4);
  int* starts = (int*)alloc((size_t)3*Bn*RRn*4);
  int* cursor = (int*)alloc((size_t)3*Bn*RRn*4);
  int* sorted = (int*)alloc((size_t)3*BT*4);
  u16* arena  = (u16*)alloc((size_t)52*16384*2);
  u16* buf0   = (u16*)alloc(2*SSTR*2);   // [stream][BT][128]
  u16* buf1   = (u16*)alloc(2*SSTR*2);
  u16* bufP   = (u16*)alloc(2*SSTR*2);
  u16* cbuf   = (u16*)alloc(2*SSTR*2);
  if (off > ws_size) return;

  hipMemsetAsync(cnt32, 0, (size_t)3*Bn*RRn*4, stream);
  k_prep<<<52, 256, 0, stream>>>(bw0, bw1, bws, cw0, cw1, cws, fcw, fccw, arena);
  k_idx <<<BT/256, 256, 0, stream>>>(p, idx);
  k_hist<<<(3*BT)/256, 256, 0, stream>>>(idx, cnt32);
  k_scan<<<24, 256, 0, stream>>>(cnt32, starts, cursor);
  k_fill<<<(3*BT)/256, 256, 0, stream>>>(idx, cursor, sorted);

  // block 0 with fused projection -> buf1
  k_rb<1><<<dim3(BT/128, 2), 512, 0, stream>>>(
      nullptr, nullptr, p, p2, wp, bp, wp2, bp2,
      arena, 0, 1, 15, 16, 10, 25,
      bb0, cb0, bb1, cb1, nullptr, nullptr, buf1);
  u16* net = buf1; u16* other = buf0;
  for (int blk = 1; blk < 4; ++blk) {
    k_pool<<<dim3((BT*16)/256, 2), 256, 0, stream>>>(idx, starts, cnt32, sorted, net, bufP);
    k_rb<0><<<dim3(BT/128, 2), 512, 0, stream>>>(
        net, bufP, nullptr, nullptr, nullptr, nullptr, nullptr, nullptr,
        arena, 2*blk, 2*blk+1, 15+2*blk, 16+2*blk, 10+blk, 25,
        bb0 + blk*128, cb0 + blk*128, bb1 + blk*128, cb1 + blk*128,
        nullptr, nullptr, other);
    u16* t = net; net = other; other = t;
  }
  // block 4 fused with final fc -> cbuf
  k_pool<<<dim3((BT*16)/256, 2), 256, 0, stream>>>(idx, starts, cnt32, sorted, net, bufP);
  k_rb<2><<<dim3(BT/128, 2), 512, 0, stream>>>(
      net, bufP, nullptr, nullptr, nullptr, nullptr, nullptr, nullptr,
      arena, 8, 9, 23, 24, 14, 25,
      bb0 + 4*128, cb0 + 4*128, bb1 + 4*128, cb1 + 4*128, fcb, fccb, cbuf);

  // scatter-mean: all 6 planes, full coverage (zeros for empty bins)
  k_mean<<<3072, 256, 0, stream>>>(starts, cnt32, sorted, cbuf, out);
}